// Round 1
// baseline (2411.702 us; speedup 1.0000x reference)
//
#include <hip/hip_runtime.h>
#include <math.h>

#define LATD 32
#define AV 40
#define NBOND 4
#define BATCH 256
#define LSRC 400
#define NT 38400
#define NA 38400
#define NBD 76800

// ---------------------------------------------------------------------------
// init: zero the 8-float accumulator block in ws
// ---------------------------------------------------------------------------
__global__ void init_kernel(float* acc) {
    if (threadIdx.x < 8) acc[threadIdx.x] = 0.0f;
}

// ---------------------------------------------------------------------------
// q-projection GEMM: q[M,32] = X[M,DIN] @ Aw[32,DIN]^T + Ab
// BM=128, BN=32, BK=32, 256 threads, micro-tile 8 rows x 2 cols
// ---------------------------------------------------------------------------
template<int DIN>
__global__ __launch_bounds__(256) void qgemm_kernel(
    const float* __restrict__ X,
    const float* __restrict__ Aw,
    const float* __restrict__ Ab,
    float* __restrict__ qout,
    int M)
{
    __shared__ __align__(16) float As[32][132];  // [k][row], padded
    __shared__ __align__(16) float Bs[32][36];   // [k][col], padded

    const int tid = threadIdx.x;
    const int row0 = blockIdx.x * 128;
    const int ty = tid >> 4;   // 0..15 -> rows ty*8..ty*8+7
    const int tx = tid & 15;   // 0..15 -> cols tx*2, tx*2+1

    float acc[8][2];
#pragma unroll
    for (int i = 0; i < 8; ++i) { acc[i][0] = 0.f; acc[i][1] = 0.f; }

    const int lrow = tid >> 1;           // 0..127
    const int lkq  = (tid & 1) * 16;     // 0 or 16
    const int bc   = tid >> 3;           // 0..31
    const int bkq  = (tid & 7) * 4;      // 0..28

    for (int k0 = 0; k0 < DIN; k0 += 32) {
        // A tile: 128 rows x 32 k (each thread: 16 floats of one row)
        {
            const float* ap = X + (size_t)(row0 + lrow) * DIN + k0 + lkq;
#pragma unroll
            for (int q = 0; q < 4; ++q) {
                float4 a = *(const float4*)(ap + q * 4);
                As[lkq + q * 4 + 0][lrow] = a.x;
                As[lkq + q * 4 + 1][lrow] = a.y;
                As[lkq + q * 4 + 2][lrow] = a.z;
                As[lkq + q * 4 + 3][lrow] = a.w;
            }
        }
        // B tile: Aw[32,32-chunk]
        {
            float4 b = *(const float4*)(Aw + (size_t)bc * DIN + k0 + bkq);
            Bs[bkq + 0][bc] = b.x;
            Bs[bkq + 1][bc] = b.y;
            Bs[bkq + 2][bc] = b.z;
            Bs[bkq + 3][bc] = b.w;
        }
        __syncthreads();
#pragma unroll 8
        for (int k = 0; k < 32; ++k) {
            float4 a0 = *(const float4*)&As[k][ty * 8];
            float4 a1 = *(const float4*)&As[k][ty * 8 + 4];
            float b0 = Bs[k][tx * 2];
            float b1 = Bs[k][tx * 2 + 1];
            acc[0][0] += a0.x * b0; acc[0][1] += a0.x * b1;
            acc[1][0] += a0.y * b0; acc[1][1] += a0.y * b1;
            acc[2][0] += a0.z * b0; acc[2][1] += a0.z * b1;
            acc[3][0] += a0.w * b0; acc[3][1] += a0.w * b1;
            acc[4][0] += a1.x * b0; acc[4][1] += a1.x * b1;
            acc[5][0] += a1.y * b0; acc[5][1] += a1.y * b1;
            acc[6][0] += a1.z * b0; acc[6][1] += a1.z * b1;
            acc[7][0] += a1.w * b0; acc[7][1] += a1.w * b1;
        }
        __syncthreads();
    }
    const float bias0 = Ab[tx * 2];
    const float bias1 = Ab[tx * 2 + 1];
#pragma unroll
    for (int i = 0; i < 8; ++i) {
        size_t r = (size_t)(row0 + ty * 8 + i);
        float2 v; v.x = acc[i][0] + bias0; v.y = acc[i][1] + bias1;
        *(float2*)(qout + r * 32 + tx * 2) = v;
    }
}

// ---------------------------------------------------------------------------
// attention: one wave per prediction row, flash-style online softmax.
// cxt[row] = softmax(src[idx[row]] @ q[row]) @ src[idx[row]]
// ---------------------------------------------------------------------------
__global__ __launch_bounds__(256) void attn_kernel(
    const float* __restrict__ src,   // [B, 400, 32]
    const int* __restrict__ idx,     // [N]
    const float* __restrict__ qbuf,  // [N, 32]
    float* __restrict__ cxt,         // [N, 32]
    int N)
{
    const int wave = threadIdx.x >> 6;
    const int lane = threadIdx.x & 63;
    const int row = blockIdx.x * 4 + wave;
    if (row >= N) return;

    const float* sg = src + (size_t)idx[row] * (LSRC * LATD);

    float qv[32];
    {
        const float4* qp = (const float4*)(qbuf + (size_t)row * 32);
#pragma unroll
        for (int i = 0; i < 8; ++i) {
            float4 t = qp[i];
            qv[i * 4 + 0] = t.x; qv[i * 4 + 1] = t.y;
            qv[i * 4 + 2] = t.z; qv[i * 4 + 3] = t.w;
        }
    }

    float m = -INFINITY, ssum = 0.0f;
    float acc[32];
#pragma unroll
    for (int d = 0; d < 32; ++d) acc[d] = 0.0f;

    for (int l = lane; l < LSRC; l += 64) {
        const float4* vp = (const float4*)(sg + (size_t)l * 32);
        float v[32];
#pragma unroll
        for (int i = 0; i < 8; ++i) {
            float4 t = vp[i];
            v[i * 4 + 0] = t.x; v[i * 4 + 1] = t.y;
            v[i * 4 + 2] = t.z; v[i * 4 + 3] = t.w;
        }
        float sc = 0.0f;
#pragma unroll
        for (int d = 0; d < 32; ++d) sc += qv[d] * v[d];
        float mn = fmaxf(m, sc);
        float scale = __expf(m - mn);
        float e = __expf(sc - mn);
        ssum = ssum * scale + e;
#pragma unroll
        for (int d = 0; d < 32; ++d) acc[d] = acc[d] * scale + e * v[d];
        m = mn;
    }

    // 64-lane butterfly merge of (m, ssum, acc[32])
#pragma unroll
    for (int off = 1; off < 64; off <<= 1) {
        float mo = __shfl_xor(m, off, 64);
        float so = __shfl_xor(ssum, off, 64);
        float mn = fmaxf(m, mo);
        float e1 = __expf(m - mn);
        float e2 = __expf(mo - mn);
        ssum = ssum * e1 + so * e2;
#pragma unroll
        for (int d = 0; d < 32; ++d) {
            float ao = __shfl_xor(acc[d], off, 64);
            acc[d] = acc[d] * e1 + ao * e2;
        }
        m = mn;
    }

    if (lane == 0) {
        float inv = 1.0f / ssum;
        float4* cp = (float4*)(cxt + (size_t)row * 32);
#pragma unroll
        for (int i = 0; i < 8; ++i) {
            float4 t;
            t.x = acc[i * 4 + 0] * inv; t.y = acc[i * 4 + 1] * inv;
            t.z = acc[i * 4 + 2] * inv; t.w = acc[i * 4 + 3] * inv;
            cp[i] = t;
        }
    }
}

// ---------------------------------------------------------------------------
// MLP1 GEMM (BM=32, BN=256 full, BK=16) + fused MLP2 + loss/acc reduction.
// h = relu(concat(X,cxt) @ W1^T + b1); logits = h @ W2^T + b2; CE/BCE sum.
// ---------------------------------------------------------------------------
template<int DIN, int DO>
__global__ __launch_bounds__(256) void mlp_loss_kernel(
    const float* __restrict__ X,     // [M, DIN]
    const float* __restrict__ cxt,   // [M, 32]
    const float* __restrict__ W1,    // [256, DIN+32]
    const float* __restrict__ B1,    // [256]
    const float* __restrict__ W2,    // [DO, 256]
    const float* __restrict__ B2,    // [DO]
    const int* __restrict__ labels,  // [M]
    float* __restrict__ accum,       // [2]: loss_sum, correct_cnt
    int M)
{
    constexpr int DC = DIN + 32;
    __shared__ __align__(16) float As[16][36];        // [k][row]
    __shared__ __align__(16) float BsHs[32 * 260];    // Bs[16][260] then hs[32][260]
    __shared__ __align__(16) float lg[32][DO];

#define BS(k, c) BsHs[(k) * 260 + (c)]
#define HS(r, c) BsHs[(r) * 260 + (c)]

    const int tid = threadIdx.x;
    const int row0 = blockIdx.x * 32;
    const int ty = tid >> 5;  // 0..7 -> rows ty*4..ty*4+3
    const int tx = tid & 31;  // cols tx*8..tx*8+7

    float acc[4][8];
#pragma unroll
    for (int i = 0; i < 4; ++i)
#pragma unroll
        for (int j = 0; j < 8; ++j) acc[i][j] = 0.f;

    for (int k0 = 0; k0 < DC; k0 += 16) {
        if (tid < 128) {
            int r = tid >> 2;
            int kq = (tid & 3) * 4;
            const float* ap;
            if (k0 < DIN) ap = X + (size_t)(row0 + r) * DIN + k0 + kq;
            else          ap = cxt + (size_t)(row0 + r) * 32 + (k0 - DIN) + kq;
            float4 a = *(const float4*)ap;
            As[kq + 0][r] = a.x; As[kq + 1][r] = a.y;
            As[kq + 2][r] = a.z; As[kq + 3][r] = a.w;
        }
        {
            const float* bp = W1 + (size_t)tid * DC + k0;
#pragma unroll
            for (int q = 0; q < 4; ++q) {
                float4 b = *(const float4*)(bp + q * 4);
                BS(q * 4 + 0, tid) = b.x; BS(q * 4 + 1, tid) = b.y;
                BS(q * 4 + 2, tid) = b.z; BS(q * 4 + 3, tid) = b.w;
            }
        }
        __syncthreads();
#pragma unroll
        for (int k = 0; k < 16; ++k) {
            float4 av  = *(const float4*)&As[k][ty * 4];
            float4 bv0 = *(const float4*)&BS(k, tx * 8);
            float4 bv1 = *(const float4*)&BS(k, tx * 8 + 4);
            float b[8] = {bv0.x, bv0.y, bv0.z, bv0.w, bv1.x, bv1.y, bv1.z, bv1.w};
#pragma unroll
            for (int j = 0; j < 8; ++j) {
                acc[0][j] += av.x * b[j];
                acc[1][j] += av.y * b[j];
                acc[2][j] += av.z * b[j];
                acc[3][j] += av.w * b[j];
            }
        }
        __syncthreads();
    }

    // epilogue: h = relu(acc + b1) -> LDS (overwrites Bs space, safe after barrier)
#pragma unroll
    for (int j = 0; j < 8; ++j) {
        float bb = B1[tx * 8 + j];
#pragma unroll
        for (int i = 0; i < 4; ++i) {
            HS(ty * 4 + i, tx * 8 + j) = fmaxf(acc[i][j] + bb, 0.0f);
        }
    }
    __syncthreads();

    // MLP2: logits[32][DO]
    for (int p = tid; p < 32 * DO; p += 256) {
        int r = p / DO;
        int o = p - r * DO;
        const float4* wp = (const float4*)(W2 + (size_t)o * 256);
        const float4* hp = (const float4*)&HS(r, 0);
        float s = 0.0f;
#pragma unroll 8
        for (int kq = 0; kq < 64; ++kq) {
            float4 w = wp[kq];
            float4 h = hp[kq];
            s += w.x * h.x + w.y * h.y + w.z * h.z + w.w * h.w;
        }
        lg[r][o] = s + B2[o];
    }
    __syncthreads();

    // loss + accuracy: one row per lane of wave 0
    float loss_l = 0.0f, cnt_l = 0.0f;
    if (tid < 32) {
        int r = tid;
        int lab = labels[row0 + r];
        if (DO == 1) {
            float s = lg[r][0];
            loss_l = fmaxf(s, 0.0f) + log1pf(__expf(-fabsf(s))) - (float)lab * s;
            int pred = (s > 0.0f) ? 1 : 0;
            cnt_l = (pred == lab) ? 1.0f : 0.0f;
        } else {
            float mx = lg[r][0];
            int am = 0;
#pragma unroll
            for (int o = 1; o < DO; ++o) {
                float v = lg[r][o];
                if (v > mx) { mx = v; am = o; }
            }
            float se = 0.0f;
#pragma unroll
            for (int o = 0; o < DO; ++o) se += __expf(lg[r][o] - mx);
            float lse = mx + logf(se);
            loss_l = lse - lg[r][lab];
            cnt_l = (am == lab) ? 1.0f : 0.0f;
        }
    }
    if (tid < 64) {
#pragma unroll
        for (int off = 32; off > 0; off >>= 1) {
            loss_l += __shfl_down(loss_l, off, 64);
            cnt_l  += __shfl_down(cnt_l, off, 64);
        }
        if (tid == 0) {
            atomicAdd(accum, loss_l);
            atomicAdd(accum + 1, cnt_l);
        }
    }
#undef BS
#undef HS
}

// ---------------------------------------------------------------------------
// finalize: combine accumulators into the 4 outputs
// out = (loss, atom_acc, topo_acc, bond_acc)
// ---------------------------------------------------------------------------
__global__ void finalize_kernel(const float* __restrict__ acc, float* __restrict__ out) {
    if (threadIdx.x == 0) {
        out[0] = (acc[0] + acc[2] + acc[4]) / (float)BATCH;
        out[1] = acc[3] / (float)NA;
        out[2] = acc[1] / (float)NT;
        out[3] = acc[5] / (float)NBD;
    }
}

// ---------------------------------------------------------------------------
extern "C" void kernel_launch(void* const* d_in, const int* in_sizes, int n_in,
                              void* d_out, int out_size, void* d_ws, size_t ws_size,
                              hipStream_t stream) {
    const float* src      = (const float*)d_in[0];
    const float* topoX    = (const float*)d_in[1];
    const float* atomX    = (const float*)d_in[2];
    const float* bondX    = (const float*)d_in[3];
    const int*   topo_idx = (const int*)d_in[4];
    const int*   atom_idx = (const int*)d_in[5];
    const int*   bond_idx = (const int*)d_in[6];
    const int*   topo_lab = (const int*)d_in[7];
    const int*   atom_lab = (const int*)d_in[8];
    const int*   bond_lab = (const int*)d_in[9];
    const float* Atw = (const float*)d_in[10]; const float* Atb = (const float*)d_in[11];
    const float* Aaw = (const float*)d_in[12]; const float* Aab = (const float*)d_in[13];
    const float* Abw = (const float*)d_in[14]; const float* Abb = (const float*)d_in[15];
    const float* tW1 = (const float*)d_in[16]; const float* tB1 = (const float*)d_in[17];
    const float* tW2 = (const float*)d_in[18]; const float* tB2 = (const float*)d_in[19];
    const float* aW1 = (const float*)d_in[20]; const float* aB1 = (const float*)d_in[21];
    const float* aW2 = (const float*)d_in[22]; const float* aB2 = (const float*)d_in[23];
    const float* bW1 = (const float*)d_in[24]; const float* bB1 = (const float*)d_in[25];
    const float* bW2 = (const float*)d_in[26]; const float* bB2 = (const float*)d_in[27];
    float* out = (float*)d_out;

    char* ws = (char*)d_ws;
    float* acc  = (float*)ws;                                   // 8 floats
    float* qbuf = (float*)(ws + 256);                           // up to NBD*32 f32
    float* cxt  = (float*)(ws + 256 + (size_t)NBD * 32 * 4);    // up to NBD*32 f32

    hipLaunchKernelGGL(init_kernel, dim3(1), dim3(64), 0, stream, acc);

    // ---- topo head ----
    hipLaunchKernelGGL((qgemm_kernel<512>), dim3(NT / 128), dim3(256), 0, stream,
                       topoX, Atw, Atb, qbuf, NT);
    hipLaunchKernelGGL(attn_kernel, dim3(NT / 4), dim3(256), 0, stream,
                       src, topo_idx, qbuf, cxt, NT);
    hipLaunchKernelGGL((mlp_loss_kernel<512, 1>), dim3(NT / 32), dim3(256), 0, stream,
                       topoX, cxt, tW1, tB1, tW2, tB2, topo_lab, acc + 0, NT);

    // ---- atom head ----
    hipLaunchKernelGGL((qgemm_kernel<512>), dim3(NA / 128), dim3(256), 0, stream,
                       atomX, Aaw, Aab, qbuf, NA);
    hipLaunchKernelGGL(attn_kernel, dim3(NA / 4), dim3(256), 0, stream,
                       src, atom_idx, qbuf, cxt, NA);
    hipLaunchKernelGGL((mlp_loss_kernel<512, 40>), dim3(NA / 32), dim3(256), 0, stream,
                       atomX, cxt, aW1, aB1, aW2, aB2, atom_lab, acc + 2, NA);

    // ---- bond head ----
    hipLaunchKernelGGL((qgemm_kernel<768>), dim3(NBD / 128), dim3(256), 0, stream,
                       bondX, Abw, Abb, qbuf, NBD);
    hipLaunchKernelGGL(attn_kernel, dim3(NBD / 4), dim3(256), 0, stream,
                       src, bond_idx, qbuf, cxt, NBD);
    hipLaunchKernelGGL((mlp_loss_kernel<768, 4>), dim3(NBD / 32), dim3(256), 0, stream,
                       bondX, cxt, bW1, bB1, bW2, bB2, bond_lab, acc + 4, NBD);

    hipLaunchKernelGGL(finalize_kernel, dim3(1), dim3(64), 0, stream, acc, out);
}

// Round 2
// 1918.876 us; speedup vs baseline: 1.2568x; 1.2568x over previous
//
#include <hip/hip_runtime.h>
#include <math.h>

#define LATD 32
#define AV 40
#define NBOND 4
#define BATCH 256
#define LSRC 400
#define NT 38400
#define NA 38400
#define NBD 76800

typedef unsigned short ushort_t;
typedef short short8 __attribute__((ext_vector_type(8)));
typedef float f32x4 __attribute__((ext_vector_type(4)));
typedef unsigned short ushort4v __attribute__((ext_vector_type(4)));
typedef unsigned short ushort8v __attribute__((ext_vector_type(8)));

__device__ __forceinline__ ushort_t f2bf(float f) {
    union { float f; unsigned u; } v; v.f = f;
    unsigned r = v.u + 0x7fffu + ((v.u >> 16) & 1u);   // RTNE
    return (ushort_t)(r >> 16);
}
__device__ __forceinline__ float bf2f(ushort_t u) {
    union { unsigned u; float f; } v; v.u = ((unsigned)u) << 16;
    return v.f;
}

// ---------------------------------------------------------------------------
// init: zero loss accumulators (8 floats) + histogram counts (3*256 ints)
// ---------------------------------------------------------------------------
__global__ void init_kernel(float* acc, int* cnt) {
    int t = threadIdx.x;
    if (t < 8) acc[t] = 0.0f;
    cnt[t] = 0; cnt[t + 256] = 0; cnt[t + 512] = 0;
}

// ---------------------------------------------------------------------------
// histogram: per-block LDS histogram, one global atomic per bin per block
// ---------------------------------------------------------------------------
__global__ __launch_bounds__(256) void hist_kernel(const int* __restrict__ idx, int N,
                                                   int* __restrict__ cnt) {
    __shared__ int lc[256];
    int t = threadIdx.x;
    lc[t] = 0;
    __syncthreads();
    for (int i = blockIdx.x * 256 + t; i < N; i += gridDim.x * 256)
        atomicAdd(&lc[idx[i]], 1);
    __syncthreads();
    if (lc[t]) atomicAdd(&cnt[t], lc[t]);
}

// ---------------------------------------------------------------------------
// scan: exclusive prefix over 256 bins, 3 heads; writes cursor array
// ---------------------------------------------------------------------------
__global__ __launch_bounds__(256) void scan_kernel(const int* __restrict__ cnt,
                                                   int* __restrict__ cur) {
    __shared__ int s[256];
    int t = threadIdx.x;
    for (int h = 0; h < 3; ++h) {
        int v = cnt[h * 256 + t];
        s[t] = v;
        __syncthreads();
        for (int d = 1; d < 256; d <<= 1) {
            int u = (t >= d) ? s[t - d] : 0;
            __syncthreads();
            s[t] += u;
            __syncthreads();
        }
        cur[h * 256 + t] = s[t] - v;   // exclusive prefix
        __syncthreads();
    }
}

// ---------------------------------------------------------------------------
// scatter: bucket[pos] = row, pos = cursor[molecule]++
// ---------------------------------------------------------------------------
__global__ __launch_bounds__(256) void scatter_kernel(const int* __restrict__ idx, int N,
                                                      int* __restrict__ cur,
                                                      int* __restrict__ bucket) {
    for (int i = blockIdx.x * 256 + threadIdx.x; i < N; i += gridDim.x * 256) {
        int b = idx[i];
        int p = atomicAdd(&cur[b], 1);
        bucket[p] = i;
    }
}

// ---------------------------------------------------------------------------
// q-projection GEMM (fp32, unchanged): q[M,32] = X[M,DIN] @ Aw^T + Ab
// ---------------------------------------------------------------------------
template<int DIN>
__global__ __launch_bounds__(256) void qgemm_kernel(
    const float* __restrict__ X,
    const float* __restrict__ Aw,
    const float* __restrict__ Ab,
    float* __restrict__ qout,
    int M)
{
    __shared__ __align__(16) float As[32][132];
    __shared__ __align__(16) float Bs[32][36];

    const int tid = threadIdx.x;
    const int row0 = blockIdx.x * 128;
    const int ty = tid >> 4;
    const int tx = tid & 15;

    float acc[8][2];
#pragma unroll
    for (int i = 0; i < 8; ++i) { acc[i][0] = 0.f; acc[i][1] = 0.f; }

    const int lrow = tid >> 1;
    const int lkq  = (tid & 1) * 16;
    const int bc   = tid >> 3;
    const int bkq  = (tid & 7) * 4;

    for (int k0 = 0; k0 < DIN; k0 += 32) {
        {
            const float* ap = X + (size_t)(row0 + lrow) * DIN + k0 + lkq;
#pragma unroll
            for (int q = 0; q < 4; ++q) {
                float4 a = *(const float4*)(ap + q * 4);
                As[lkq + q * 4 + 0][lrow] = a.x;
                As[lkq + q * 4 + 1][lrow] = a.y;
                As[lkq + q * 4 + 2][lrow] = a.z;
                As[lkq + q * 4 + 3][lrow] = a.w;
            }
        }
        {
            float4 b = *(const float4*)(Aw + (size_t)bc * DIN + k0 + bkq);
            Bs[bkq + 0][bc] = b.x;
            Bs[bkq + 1][bc] = b.y;
            Bs[bkq + 2][bc] = b.z;
            Bs[bkq + 3][bc] = b.w;
        }
        __syncthreads();
#pragma unroll 8
        for (int k = 0; k < 32; ++k) {
            float4 a0 = *(const float4*)&As[k][ty * 8];
            float4 a1 = *(const float4*)&As[k][ty * 8 + 4];
            float b0 = Bs[k][tx * 2];
            float b1 = Bs[k][tx * 2 + 1];
            acc[0][0] += a0.x * b0; acc[0][1] += a0.x * b1;
            acc[1][0] += a0.y * b0; acc[1][1] += a0.y * b1;
            acc[2][0] += a0.z * b0; acc[2][1] += a0.z * b1;
            acc[3][0] += a0.w * b0; acc[3][1] += a0.w * b1;
            acc[4][0] += a1.x * b0; acc[4][1] += a1.x * b1;
            acc[5][0] += a1.y * b0; acc[5][1] += a1.y * b1;
            acc[6][0] += a1.z * b0; acc[6][1] += a1.z * b1;
            acc[7][0] += a1.w * b0; acc[7][1] += a1.w * b1;
        }
        __syncthreads();
    }
    const float bias0 = Ab[tx * 2];
    const float bias1 = Ab[tx * 2 + 1];
#pragma unroll
    for (int i = 0; i < 8; ++i) {
        size_t r = (size_t)(row0 + ty * 8 + i);
        float2 v; v.x = acc[i][0] + bias0; v.y = acc[i][1] + bias1;
        *(float2*)(qout + r * 32 + tx * 2) = v;
    }
}

// ---------------------------------------------------------------------------
// attention: one wave per prediction row, bucket-ordered rows for L1/L2 reuse
// of the per-molecule src slice. Output written as bf16.
// ---------------------------------------------------------------------------
__global__ __launch_bounds__(256) void attn_kernel(
    const float* __restrict__ src,     // [B, 400, 32]
    const int* __restrict__ idx,       // [N]
    const int* __restrict__ rows,      // bucket: rows sorted by molecule
    const float* __restrict__ qbuf,    // [N, 32]
    ushort_t* __restrict__ cxtb,       // [N, 32] bf16
    int N)
{
    const int wave = threadIdx.x >> 6;
    const int lane = threadIdx.x & 63;
    const int pos = blockIdx.x * 4 + wave;
    if (pos >= N) return;
    const int row = rows[pos];

    const float* sg = src + (size_t)idx[row] * (LSRC * LATD);

    float qv[32];
    {
        const float4* qp = (const float4*)(qbuf + (size_t)row * 32);
#pragma unroll
        for (int i = 0; i < 8; ++i) {
            float4 t = qp[i];
            qv[i * 4 + 0] = t.x; qv[i * 4 + 1] = t.y;
            qv[i * 4 + 2] = t.z; qv[i * 4 + 3] = t.w;
        }
    }

    float m = -INFINITY, ssum = 0.0f;
    float acc[32];
#pragma unroll
    for (int d = 0; d < 32; ++d) acc[d] = 0.0f;

    for (int l = lane; l < LSRC; l += 64) {
        const float4* vp = (const float4*)(sg + (size_t)l * 32);
        float v[32];
#pragma unroll
        for (int i = 0; i < 8; ++i) {
            float4 t = vp[i];
            v[i * 4 + 0] = t.x; v[i * 4 + 1] = t.y;
            v[i * 4 + 2] = t.z; v[i * 4 + 3] = t.w;
        }
        float sc = 0.0f;
#pragma unroll
        for (int d = 0; d < 32; ++d) sc += qv[d] * v[d];
        float mn = fmaxf(m, sc);
        float scale = __expf(m - mn);
        float e = __expf(sc - mn);
        ssum = ssum * scale + e;
#pragma unroll
        for (int d = 0; d < 32; ++d) acc[d] = acc[d] * scale + e * v[d];
        m = mn;
    }

#pragma unroll
    for (int off = 1; off < 64; off <<= 1) {
        float mo = __shfl_xor(m, off, 64);
        float so = __shfl_xor(ssum, off, 64);
        float mn = fmaxf(m, mo);
        float e1 = __expf(m - mn);
        float e2 = __expf(mo - mn);
        ssum = ssum * e1 + so * e2;
#pragma unroll
        for (int d = 0; d < 32; ++d) {
            float ao = __shfl_xor(acc[d], off, 64);
            acc[d] = acc[d] * e1 + ao * e2;
        }
        m = mn;
    }

    if (lane == 0) {
        float inv = 1.0f / ssum;
#pragma unroll
        for (int i = 0; i < 8; ++i) {
            ushort4v o;
            o[0] = f2bf(acc[i * 4 + 0] * inv);
            o[1] = f2bf(acc[i * 4 + 1] * inv);
            o[2] = f2bf(acc[i * 4 + 2] * inv);
            o[3] = f2bf(acc[i * 4 + 3] * inv);
            *(ushort4v*)(cxtb + (size_t)row * 32 + i * 4) = o;
        }
    }
}

// ---------------------------------------------------------------------------
// MLP1 via bf16 MFMA 16x16x32 (BM=64, BN=256, BK=32), inline fp32->bf16
// staging, fused MLP2 (fp32 from bf16 LDS) + CE/BCE loss + accuracy.
// ---------------------------------------------------------------------------
template<int DIN, int DO>
__global__ __launch_bounds__(256) void mlp_mfma_kernel(
    const float* __restrict__ X,       // [M, DIN] fp32
    const ushort_t* __restrict__ cxtb, // [M, 32] bf16
    const float* __restrict__ W1,      // [256, DIN+32] fp32
    const float* __restrict__ B1,      // [256]
    const float* __restrict__ W2,      // [DO, 256] fp32
    const float* __restrict__ B2,      // [DO]
    const int* __restrict__ labels,    // [M]
    float* __restrict__ accum,         // [2]: loss_sum, correct_cnt
    int M)
{
    constexpr int DC = DIN + 32;
    constexpr int KITERS = DC / 32;

    __shared__ ushort_t sAB[10240];      // As[64][32] (2048) + Bs[256][32] (8192)
    __shared__ ushort_t HS[64 * 256];    // h, bf16
    __shared__ float lg[64 * DO];

    ushort_t* As = sAB;
    ushort_t* Bs = sAB + 2048;

    const int tid = threadIdx.x;
    const int row0 = blockIdx.x * 64;
    const int wave = tid >> 6;
    const int lane = tid & 63;
    const int l15 = lane & 15;
    const int l4 = lane >> 4;

    f32x4 acc[4][4];
#pragma unroll
    for (int mi = 0; mi < 4; ++mi)
#pragma unroll
        for (int ni = 0; ni < 4; ++ni)
            acc[mi][ni] = (f32x4){0.f, 0.f, 0.f, 0.f};

    for (int it = 0; it < KITERS; ++it) {
        const int k0 = it * 32;
        // stage A tile: 64 rows x 32 k (bf16)
#pragma unroll
        for (int half = 0; half < 2; ++half) {
            int f = tid + half * 256;
            int row = f >> 3, k4 = (f & 7) * 4;
            ushort4v pk;
            if (k0 < DIN) {
                float4 v = *(const float4*)(X + (size_t)(row0 + row) * DIN + k0 + k4);
                pk[0] = f2bf(v.x); pk[1] = f2bf(v.y);
                pk[2] = f2bf(v.z); pk[3] = f2bf(v.w);
            } else {
                pk = *(const ushort4v*)(cxtb + (size_t)(row0 + row) * 32 + k4);
            }
            *(ushort4v*)&As[row * 32 + k4] = pk;
        }
        // stage B tile: W1 256 rows x 32 k (bf16)
#pragma unroll
        for (int i = 0; i < 8; ++i) {
            int f = tid + i * 256;
            int n = f >> 3, k4 = (f & 7) * 4;
            float4 v = *(const float4*)(W1 + (size_t)n * DC + k0 + k4);
            ushort4v pk;
            pk[0] = f2bf(v.x); pk[1] = f2bf(v.y);
            pk[2] = f2bf(v.z); pk[3] = f2bf(v.w);
            *(ushort4v*)&Bs[n * 32 + k4] = pk;
        }
        __syncthreads();

        short8 af[4], bfv[4];
#pragma unroll
        for (int mi = 0; mi < 4; ++mi)
            af[mi] = *(const short8*)&As[(mi * 16 + l15) * 32 + l4 * 8];
#pragma unroll
        for (int ni = 0; ni < 4; ++ni)
            bfv[ni] = *(const short8*)&Bs[(wave * 64 + ni * 16 + l15) * 32 + l4 * 8];
#pragma unroll
        for (int mi = 0; mi < 4; ++mi)
#pragma unroll
            for (int ni = 0; ni < 4; ++ni)
                acc[mi][ni] = __builtin_amdgcn_mfma_f32_16x16x32_bf16(
                    af[mi], bfv[ni], acc[mi][ni], 0, 0, 0);
        __syncthreads();
    }

    // epilogue: h = relu(acc + b1) -> HS (bf16). C layout: col=lane&15, row=l4*4+reg
    float b1v[4];
#pragma unroll
    for (int ni = 0; ni < 4; ++ni) b1v[ni] = B1[wave * 64 + ni * 16 + l15];
#pragma unroll
    for (int mi = 0; mi < 4; ++mi) {
#pragma unroll
        for (int ni = 0; ni < 4; ++ni) {
            int col = wave * 64 + ni * 16 + l15;
#pragma unroll
            for (int r = 0; r < 4; ++r) {
                int rowl = mi * 16 + l4 * 4 + r;
                float h = fmaxf(acc[mi][ni][r] + b1v[ni], 0.0f);
                HS[rowl * 256 + col] = f2bf(h);
            }
        }
    }
    // stage W2 (bf16) into sAB (safe: k-loop ended with a barrier)
#pragma unroll 4
    for (int j = 0; j < DO; ++j)
        sAB[j * 256 + tid] = f2bf(W2[(size_t)j * 256 + tid]);
    __syncthreads();

    // MLP2: logits[64][DO] from bf16 h and bf16 W2
    for (int p = tid; p < 64 * DO; p += 256) {
        int r = p / DO, o = p - (p / DO) * DO;
        float s = 0.0f;
#pragma unroll 4
        for (int kk = 0; kk < 32; ++kk) {
            ushort8v hv = *(const ushort8v*)&HS[r * 256 + kk * 8];
            ushort8v wv = *(const ushort8v*)&sAB[o * 256 + kk * 8];
#pragma unroll
            for (int e = 0; e < 8; ++e) s += bf2f(hv[e]) * bf2f(wv[e]);
        }
        lg[p] = s + B2[o];
    }
    __syncthreads();

    // loss + accuracy: lane per row (wave 0)
    float loss_l = 0.0f, cnt_l = 0.0f;
    if (tid < 64) {
        int lab = labels[row0 + tid];
        if (DO == 1) {
            float s = lg[tid];
            loss_l = fmaxf(s, 0.0f) + log1pf(__expf(-fabsf(s))) - (float)lab * s;
            int pred = (s > 0.0f) ? 1 : 0;
            cnt_l = (pred == lab) ? 1.0f : 0.0f;
        } else {
            const float* lr = &lg[tid * DO];
            float mx = lr[0];
            int am = 0;
#pragma unroll
            for (int o = 1; o < DO; ++o) {
                float v = lr[o];
                if (v > mx) { mx = v; am = o; }
            }
            float se = 0.0f;
#pragma unroll
            for (int o = 0; o < DO; ++o) se += __expf(lr[o] - mx);
            loss_l = mx + logf(se) - lr[lab];
            cnt_l = (am == lab) ? 1.0f : 0.0f;
        }
#pragma unroll
        for (int off = 32; off > 0; off >>= 1) {
            loss_l += __shfl_down(loss_l, off, 64);
            cnt_l  += __shfl_down(cnt_l, off, 64);
        }
        if (tid == 0) {
            atomicAdd(accum, loss_l);
            atomicAdd(accum + 1, cnt_l);
        }
    }
}

// ---------------------------------------------------------------------------
__global__ void finalize_kernel(const float* __restrict__ acc, float* __restrict__ out) {
    if (threadIdx.x == 0) {
        out[0] = (acc[0] + acc[2] + acc[4]) / (float)BATCH;
        out[1] = acc[3] / (float)NA;
        out[2] = acc[1] / (float)NT;
        out[3] = acc[5] / (float)NBD;
    }
}

// ---------------------------------------------------------------------------
extern "C" void kernel_launch(void* const* d_in, const int* in_sizes, int n_in,
                              void* d_out, int out_size, void* d_ws, size_t ws_size,
                              hipStream_t stream) {
    const float* src      = (const float*)d_in[0];
    const float* topoX    = (const float*)d_in[1];
    const float* atomX    = (const float*)d_in[2];
    const float* bondX    = (const float*)d_in[3];
    const int*   topo_idx = (const int*)d_in[4];
    const int*   atom_idx = (const int*)d_in[5];
    const int*   bond_idx = (const int*)d_in[6];
    const int*   topo_lab = (const int*)d_in[7];
    const int*   atom_lab = (const int*)d_in[8];
    const int*   bond_lab = (const int*)d_in[9];
    const float* Atw = (const float*)d_in[10]; const float* Atb = (const float*)d_in[11];
    const float* Aaw = (const float*)d_in[12]; const float* Aab = (const float*)d_in[13];
    const float* Abw = (const float*)d_in[14]; const float* Abb = (const float*)d_in[15];
    const float* tW1 = (const float*)d_in[16]; const float* tB1 = (const float*)d_in[17];
    const float* tW2 = (const float*)d_in[18]; const float* tB2 = (const float*)d_in[19];
    const float* aW1 = (const float*)d_in[20]; const float* aB1 = (const float*)d_in[21];
    const float* aW2 = (const float*)d_in[22]; const float* aB2 = (const float*)d_in[23];
    const float* bW1 = (const float*)d_in[24]; const float* bB1 = (const float*)d_in[25];
    const float* bW2 = (const float*)d_in[26]; const float* bB2 = (const float*)d_in[27];
    float* out = (float*)d_out;

    char* ws = (char*)d_ws;
    float* acc   = (float*)ws;                          // 8 floats
    int*   cnt   = (int*)(ws + 256);                    // 3*256
    int*   cur   = (int*)(ws + 3328);                   // 3*256
    int*   bkt_t = (int*)(ws + 8192);                   // NT
    int*   bkt_a = bkt_t + NT;                          // NA
    int*   bkt_b = bkt_a + NA;                          // NBD
    float* qbuf  = (float*)(ws + 622592);               // NBD*32 fp32
    ushort_t* cxtb = (ushort_t*)(ws + 10452992);        // NBD*32 bf16

    hipLaunchKernelGGL(init_kernel, dim3(1), dim3(256), 0, stream, acc, cnt);

    hipLaunchKernelGGL(hist_kernel, dim3(128), dim3(256), 0, stream, topo_idx, NT, cnt + 0);
    hipLaunchKernelGGL(hist_kernel, dim3(128), dim3(256), 0, stream, atom_idx, NA, cnt + 256);
    hipLaunchKernelGGL(hist_kernel, dim3(128), dim3(256), 0, stream, bond_idx, NBD, cnt + 512);
    hipLaunchKernelGGL(scan_kernel, dim3(1), dim3(256), 0, stream, cnt, cur);
    hipLaunchKernelGGL(scatter_kernel, dim3(256), dim3(256), 0, stream, topo_idx, NT, cur + 0, bkt_t);
    hipLaunchKernelGGL(scatter_kernel, dim3(256), dim3(256), 0, stream, atom_idx, NA, cur + 256, bkt_a);
    hipLaunchKernelGGL(scatter_kernel, dim3(256), dim3(256), 0, stream, bond_idx, NBD, cur + 512, bkt_b);

    // ---- topo head ----
    hipLaunchKernelGGL((qgemm_kernel<512>), dim3(NT / 128), dim3(256), 0, stream,
                       topoX, Atw, Atb, qbuf, NT);
    hipLaunchKernelGGL(attn_kernel, dim3(NT / 4), dim3(256), 0, stream,
                       src, topo_idx, bkt_t, qbuf, cxtb, NT);
    hipLaunchKernelGGL((mlp_mfma_kernel<512, 1>), dim3(NT / 64), dim3(256), 0, stream,
                       topoX, cxtb, tW1, tB1, tW2, tB2, topo_lab, acc + 0, NT);

    // ---- atom head ----
    hipLaunchKernelGGL((qgemm_kernel<512>), dim3(NA / 128), dim3(256), 0, stream,
                       atomX, Aaw, Aab, qbuf, NA);
    hipLaunchKernelGGL(attn_kernel, dim3(NA / 4), dim3(256), 0, stream,
                       src, atom_idx, bkt_a, qbuf, cxtb, NA);
    hipLaunchKernelGGL((mlp_mfma_kernel<512, 40>), dim3(NA / 64), dim3(256), 0, stream,
                       atomX, cxtb, aW1, aB1, aW2, aB2, atom_lab, acc + 2, NA);

    // ---- bond head ----
    hipLaunchKernelGGL((qgemm_kernel<768>), dim3(NBD / 128), dim3(256), 0, stream,
                       bondX, Abw, Abb, qbuf, NBD);
    hipLaunchKernelGGL(attn_kernel, dim3(NBD / 4), dim3(256), 0, stream,
                       src, bond_idx, bkt_b, qbuf, cxtb, NBD);
    hipLaunchKernelGGL((mlp_mfma_kernel<768, 4>), dim3(NBD / 64), dim3(256), 0, stream,
                       bondX, cxtb, bW1, bB1, bW2, bB2, bond_lab, acc + 4, NBD);

    hipLaunchKernelGGL(finalize_kernel, dim3(1), dim3(64), 0, stream, acc, out);
}

// Round 3
// 1329.773 us; speedup vs baseline: 1.8136x; 1.4430x over previous
//
#include <hip/hip_runtime.h>
#include <math.h>

#define LATD 32
#define AV 40
#define NBOND 4
#define BATCH 256
#define LSRC 400
#define NT 38400
#define NA 38400
#define NBD 76800

typedef unsigned short ushort_t;
typedef short short8 __attribute__((ext_vector_type(8)));
typedef float f32x4 __attribute__((ext_vector_type(4)));
typedef unsigned short ushort4v __attribute__((ext_vector_type(4)));
typedef unsigned short ushort8v __attribute__((ext_vector_type(8)));

__device__ __forceinline__ ushort_t f2bf(float f) {
    union { float f; unsigned u; } v; v.f = f;
    unsigned r = v.u + 0x7fffu + ((v.u >> 16) & 1u);   // RTNE
    return (ushort_t)(r >> 16);
}
__device__ __forceinline__ float bf2f(ushort_t u) {
    union { unsigned u; float f; } v; v.u = ((unsigned)u) << 16;
    return v.f;
}

// ---------------------------------------------------------------------------
// init: zero loss accumulators (8 floats) + histogram counts (3*256 ints)
// ---------------------------------------------------------------------------
__global__ void init_kernel(float* acc, int* cnt) {
    int t = threadIdx.x;
    if (t < 8) acc[t] = 0.0f;
    cnt[t] = 0; cnt[t + 256] = 0; cnt[t + 512] = 0;
}

// ---------------------------------------------------------------------------
// histogram
// ---------------------------------------------------------------------------
__global__ __launch_bounds__(256) void hist_kernel(const int* __restrict__ idx, int N,
                                                   int* __restrict__ cnt) {
    __shared__ int lc[256];
    int t = threadIdx.x;
    lc[t] = 0;
    __syncthreads();
    for (int i = blockIdx.x * 256 + t; i < N; i += gridDim.x * 256)
        atomicAdd(&lc[idx[i]], 1);
    __syncthreads();
    if (lc[t]) atomicAdd(&cnt[t], lc[t]);
}

// ---------------------------------------------------------------------------
// scan: exclusive prefix over 256 bins, 3 heads; writes mutable cursor AND
// preserved bucket-start arrays
// ---------------------------------------------------------------------------
__global__ __launch_bounds__(256) void scan_kernel(const int* __restrict__ cnt,
                                                   int* __restrict__ cur,
                                                   int* __restrict__ bstart) {
    __shared__ int s[256];
    int t = threadIdx.x;
    for (int h = 0; h < 3; ++h) {
        int v = cnt[h * 256 + t];
        s[t] = v;
        __syncthreads();
        for (int d = 1; d < 256; d <<= 1) {
            int u = (t >= d) ? s[t - d] : 0;
            __syncthreads();
            s[t] += u;
            __syncthreads();
        }
        cur[h * 256 + t] = s[t] - v;
        bstart[h * 256 + t] = s[t] - v;
        __syncthreads();
    }
}

// ---------------------------------------------------------------------------
// scatter: bucket[pos] = row
// ---------------------------------------------------------------------------
__global__ __launch_bounds__(256) void scatter_kernel(const int* __restrict__ idx, int N,
                                                      int* __restrict__ cur,
                                                      int* __restrict__ bucket) {
    for (int i = blockIdx.x * 256 + threadIdx.x; i < N; i += gridDim.x * 256) {
        int b = idx[i];
        int p = atomicAdd(&cur[b], 1);
        bucket[p] = i;
    }
}

// ---------------------------------------------------------------------------
// Fused attention: per (molecule, 32-row tile) block.
//   Q = X_rows @ Aw^T + Ab            (MFMA, K-loop over DIN)
//   S = Q @ src^T                     (MFMA, src staged row-major bf16 in LDS)
//   softmax over 400 (register-space stats + butterfly + wave-pair merge)
//   O = P @ src                       (MFMA, src staged transposed bf16 in LDS)
// cxtb[row] = O (bf16).
// LDS 62.3 KB -> 2 blocks/CU. sP aliases sQ+sSrcRow (barrier-separated).
// ---------------------------------------------------------------------------
template<int DIN, int MAXT>
__global__ __launch_bounds__(256) void attn_fused_kernel(
    const float* __restrict__ src,     // [256, 400, 32]
    const float* __restrict__ X,       // [N, DIN]
    const float* __restrict__ Aw,      // [32, DIN]
    const float* __restrict__ Ab,      // [32]
    const int* __restrict__ bucket,
    const int* __restrict__ bstart,    // [256]
    const int* __restrict__ cnt,       // [256]
    ushort_t* __restrict__ cxtb)       // [N, 32] bf16
{
    const int m = blockIdx.x / MAXT;
    const int t = blockIdx.x % MAXT;
    const int cm = cnt[m];
    if (t * 32 >= cm) return;

    __shared__ __align__(16) char smem[62336];
    ushort_t* sQ      = (ushort_t*)(smem);            // [32][40]           2560 B
    ushort_t* sSrcRow = (ushort_t*)(smem + 2560);     // [400][40]         32000 B
    ushort_t* sXA     = (ushort_t*)(smem + 2560);     // [32][72] staging (aliases sSrcRow)
    ushort_t* sW      = (ushort_t*)(smem + 2560 + 4608); // [32][72] staging
    ushort_t* sP      = (ushort_t*)(smem);            // [32][424] aliases sQ+sSrcRow
    ushort_t* sSrcT   = (ushort_t*)(smem + 34560);    // [32][424]         27136 B
    float*    sStats  = (float*)(smem + 61696);       // [4][16][2]          512 B
    int*      sRows   = (int*)(smem + 62208);         // [32]                128 B

    const int tid = threadIdx.x;
    const int wave = tid >> 6, lane = tid & 63;
    const int l15 = lane & 15, quad = lane >> 4;
    const int mt = wave & 1;        // M-tile (16 rows)
    const int nt = wave >> 1;       // N-tile / chunk-parity

    if (tid < 32) {
        int p = t * 32 + tid;
        sRows[tid] = (p < cm) ? bucket[bstart[m] + p] : -1;
    }
    __syncthreads();

    // ---- Q projection ----
    const int srow = tid >> 3;          // 0..31 staged row
    const int sko  = (tid & 7) * 8;     // 0..56 k offset
    const int g_s  = sRows[srow];

    f32x4 qacc = {0.f, 0.f, 0.f, 0.f};
    for (int k0 = 0; k0 < DIN; k0 += 64) {
        float4 v0 = {0,0,0,0}, v1 = {0,0,0,0};
        if (g_s >= 0) {
            const float* xb = X + (size_t)g_s * DIN + k0 + sko;
            v0 = *(const float4*)xb; v1 = *(const float4*)(xb + 4);
        }
        ushort8v px;
        px[0]=f2bf(v0.x); px[1]=f2bf(v0.y); px[2]=f2bf(v0.z); px[3]=f2bf(v0.w);
        px[4]=f2bf(v1.x); px[5]=f2bf(v1.y); px[6]=f2bf(v1.z); px[7]=f2bf(v1.w);
        *(ushort8v*)&sXA[srow * 72 + sko] = px;
        const float* wb = Aw + (size_t)srow * DIN + k0 + sko;
        float4 w0 = *(const float4*)wb, w1 = *(const float4*)(wb + 4);
        ushort8v pw;
        pw[0]=f2bf(w0.x); pw[1]=f2bf(w0.y); pw[2]=f2bf(w0.z); pw[3]=f2bf(w0.w);
        pw[4]=f2bf(w1.x); pw[5]=f2bf(w1.y); pw[6]=f2bf(w1.z); pw[7]=f2bf(w1.w);
        *(ushort8v*)&sW[srow * 72 + sko] = pw;
        __syncthreads();
        short8 a0 = *(const short8*)&sXA[(mt*16 + l15)*72 + quad*8];
        short8 a1 = *(const short8*)&sXA[(mt*16 + l15)*72 + 32 + quad*8];
        short8 b0 = *(const short8*)&sW[(nt*16 + l15)*72 + quad*8];
        short8 b1 = *(const short8*)&sW[(nt*16 + l15)*72 + 32 + quad*8];
        qacc = __builtin_amdgcn_mfma_f32_16x16x32_bf16(a0, b0, qacc, 0, 0, 0);
        qacc = __builtin_amdgcn_mfma_f32_16x16x32_bf16(a1, b1, qacc, 0, 0, 0);
        __syncthreads();
    }
    {   // write Q tile (bf16) to sQ; invalid rows get q=bias (finite, unused)
        float bias = Ab[nt*16 + l15];
#pragma unroll
        for (int r = 0; r < 4; ++r)
            sQ[(mt*16 + quad*4 + r) * 40 + nt*16 + l15] = f2bf(qacc[r] + bias);
    }

    // ---- stage src slice: row-major bf16 ----
    const float4* s4 = (const float4*)(src + (size_t)m * (LSRC * LATD));
    for (int i = tid; i < 3200; i += 256) {
        float4 v = s4[i];
        int l = i >> 3, d4 = (i & 7) * 4;
        ushort4v pk;
        pk[0]=f2bf(v.x); pk[1]=f2bf(v.y); pk[2]=f2bf(v.z); pk[3]=f2bf(v.w);
        *(ushort4v*)&sSrcRow[l * 40 + d4] = pk;
    }
    __syncthreads();
    // ---- transpose to sSrcT (K-padded to 416 with zeros) ----
    for (int i = tid; i < 32 * 416; i += 256) {
        int d = i & 31, l = i >> 5;
        sSrcT[d * 424 + l] = (l < 400) ? sSrcRow[l * 40 + d] : (ushort_t)0;
    }
    __syncthreads();

    // ---- phase 1: S = Q @ src^T, chunks of 16 cols; wave covers parity nt ----
    short8 aq = *(const short8*)&sQ[(mt*16 + l15) * 40 + quad*8];
    f32x4 sc[13];
    const int nch = 13 - nt;            // nt=0: c=0,2..24 (13); nt=1: c=1,3..23 (12)
#pragma unroll
    for (int j = 0; j < 13; ++j) {
        if (j >= nch) break;
        int c = nt + 2 * j;
        short8 bv = *(const short8*)&sSrcRow[(c*16 + l15) * 40 + quad*8];
        f32x4 z = {0.f, 0.f, 0.f, 0.f};
        sc[j] = __builtin_amdgcn_mfma_f32_16x16x32_bf16(aq, bv, z, 0, 0, 0);
    }

    // per-lane stats over this wave's chunks
    float Mr[4], Sr[4];
#pragma unroll
    for (int r = 0; r < 4; ++r) {
        float mx = sc[0][r];
#pragma unroll
        for (int j = 1; j < 13; ++j) if (j < nch) mx = fmaxf(mx, sc[j][r]);
        float s = 0.f;
#pragma unroll
        for (int j = 0; j < 13; ++j) if (j < nch) s += __expf(sc[j][r] - mx);
        Mr[r] = mx; Sr[r] = s;
    }
    // butterfly across the 16 l15 lanes (stays within quad)
#pragma unroll
    for (int msk = 1; msk < 16; msk <<= 1) {
#pragma unroll
        for (int r = 0; r < 4; ++r) {
            float mo = __shfl_xor(Mr[r], msk, 64);
            float so = __shfl_xor(Sr[r], msk, 64);
            float mn = fmaxf(Mr[r], mo);
            Sr[r] = Sr[r] * __expf(Mr[r] - mn) + so * __expf(mo - mn);
            Mr[r] = mn;
        }
    }
    if (l15 == 0) {
#pragma unroll
        for (int r = 0; r < 4; ++r) {
            sStats[(wave * 16 + quad * 4 + r) * 2 + 0] = Mr[r];
            sStats[(wave * 16 + quad * 4 + r) * 2 + 1] = Sr[r];
        }
    }
    __syncthreads();   // also fences all sQ/sSrcRow frag reads before sP writes
    {
        const int pw = wave ^ 2;   // partner wave, same mt, other parity
#pragma unroll
        for (int r = 0; r < 4; ++r) {
            float mo = sStats[(pw*16 + quad*4 + r)*2 + 0];
            float so = sStats[(pw*16 + quad*4 + r)*2 + 1];
            float mn = fmaxf(Mr[r], mo);
            float L = Sr[r] * __expf(Mr[r] - mn) + so * __expf(mo - mn);
            Mr[r] = mn; Sr[r] = 1.0f / L;
        }
    }
    // ---- write P (bf16, normalized) into sP; zero K-pad cols 400..415 ----
#pragma unroll
    for (int j = 0; j < 13; ++j) {
        if (j >= nch) break;
        int col = (nt + 2 * j) * 16 + l15;
#pragma unroll
        for (int r = 0; r < 4; ++r) {
            int row = mt*16 + quad*4 + r;
            sP[row * 424 + col] = f2bf(__expf(sc[j][r] - Mr[r]) * Sr[r]);
        }
    }
    for (int i = tid; i < 512; i += 256) {
        int row = i >> 4, col = 400 + (i & 15);
        sP[row * 424 + col] = 0;
    }
    __syncthreads();

    // ---- phase 2: O = P @ src  (wave = (mt, nt) output tile) ----
    f32x4 oac = {0.f, 0.f, 0.f, 0.f};
#pragma unroll
    for (int k0 = 0; k0 < 416; k0 += 32) {
        short8 ap = *(const short8*)&sP[(mt*16 + l15) * 424 + k0 + quad*8];
        short8 bp = *(const short8*)&sSrcT[(nt*16 + l15) * 424 + k0 + quad*8];
        oac = __builtin_amdgcn_mfma_f32_16x16x32_bf16(ap, bp, oac, 0, 0, 0);
    }
    {
        int col = nt*16 + l15;
#pragma unroll
        for (int r = 0; r < 4; ++r) {
            int rowl = mt*16 + quad*4 + r;
            int g = sRows[rowl];
            if (g >= 0) cxtb[(size_t)g * 32 + col] = f2bf(oac[r]);
        }
    }
}

// ---------------------------------------------------------------------------
// MLP1 via bf16 MFMA 16x16x32 (BM=64, BN=256, BK=32) + fused MLP2 + loss.
// (unchanged from round 2)
// ---------------------------------------------------------------------------
template<int DIN, int DO>
__global__ __launch_bounds__(256) void mlp_mfma_kernel(
    const float* __restrict__ X,
    const ushort_t* __restrict__ cxtb,
    const float* __restrict__ W1,
    const float* __restrict__ B1,
    const float* __restrict__ W2,
    const float* __restrict__ B2,
    const int* __restrict__ labels,
    float* __restrict__ accum,
    int M)
{
    constexpr int DC = DIN + 32;
    constexpr int KITERS = DC / 32;

    __shared__ ushort_t sAB[10240];
    __shared__ ushort_t HS[64 * 256];
    __shared__ float lg[64 * DO];

    ushort_t* As = sAB;
    ushort_t* Bs = sAB + 2048;

    const int tid = threadIdx.x;
    const int row0 = blockIdx.x * 64;
    const int wave = tid >> 6;
    const int lane = tid & 63;
    const int l15 = lane & 15;
    const int l4 = lane >> 4;

    f32x4 acc[4][4];
#pragma unroll
    for (int mi = 0; mi < 4; ++mi)
#pragma unroll
        for (int ni = 0; ni < 4; ++ni)
            acc[mi][ni] = (f32x4){0.f, 0.f, 0.f, 0.f};

    for (int it = 0; it < KITERS; ++it) {
        const int k0 = it * 32;
#pragma unroll
        for (int half = 0; half < 2; ++half) {
            int f = tid + half * 256;
            int row = f >> 3, k4 = (f & 7) * 4;
            ushort4v pk;
            if (k0 < DIN) {
                float4 v = *(const float4*)(X + (size_t)(row0 + row) * DIN + k0 + k4);
                pk[0] = f2bf(v.x); pk[1] = f2bf(v.y);
                pk[2] = f2bf(v.z); pk[3] = f2bf(v.w);
            } else {
                pk = *(const ushort4v*)(cxtb + (size_t)(row0 + row) * 32 + k4);
            }
            *(ushort4v*)&As[row * 32 + k4] = pk;
        }
#pragma unroll
        for (int i = 0; i < 8; ++i) {
            int f = tid + i * 256;
            int n = f >> 3, k4 = (f & 7) * 4;
            float4 v = *(const float4*)(W1 + (size_t)n * DC + k0 + k4);
            ushort4v pk;
            pk[0] = f2bf(v.x); pk[1] = f2bf(v.y);
            pk[2] = f2bf(v.z); pk[3] = f2bf(v.w);
            *(ushort4v*)&Bs[n * 32 + k4] = pk;
        }
        __syncthreads();

        short8 af[4], bfv[4];
#pragma unroll
        for (int mi = 0; mi < 4; ++mi)
            af[mi] = *(const short8*)&As[(mi * 16 + l15) * 32 + l4 * 8];
#pragma unroll
        for (int ni = 0; ni < 4; ++ni)
            bfv[ni] = *(const short8*)&Bs[(wave * 64 + ni * 16 + l15) * 32 + l4 * 8];
#pragma unroll
        for (int mi = 0; mi < 4; ++mi)
#pragma unroll
            for (int ni = 0; ni < 4; ++ni)
                acc[mi][ni] = __builtin_amdgcn_mfma_f32_16x16x32_bf16(
                    af[mi], bfv[ni], acc[mi][ni], 0, 0, 0);
        __syncthreads();
    }

    float b1v[4];
#pragma unroll
    for (int ni = 0; ni < 4; ++ni) b1v[ni] = B1[wave * 64 + ni * 16 + l15];
#pragma unroll
    for (int mi = 0; mi < 4; ++mi) {
#pragma unroll
        for (int ni = 0; ni < 4; ++ni) {
            int col = wave * 64 + ni * 16 + l15;
#pragma unroll
            for (int r = 0; r < 4; ++r) {
                int rowl = mi * 16 + l4 * 4 + r;
                float h = fmaxf(acc[mi][ni][r] + b1v[ni], 0.0f);
                HS[rowl * 256 + col] = f2bf(h);
            }
        }
    }
#pragma unroll 4
    for (int j = 0; j < DO; ++j)
        sAB[j * 256 + tid] = f2bf(W2[(size_t)j * 256 + tid]);
    __syncthreads();

    for (int p = tid; p < 64 * DO; p += 256) {
        int r = p / DO, o = p - (p / DO) * DO;
        float s = 0.0f;
#pragma unroll 4
        for (int kk = 0; kk < 32; ++kk) {
            ushort8v hv = *(const ushort8v*)&HS[r * 256 + kk * 8];
            ushort8v wv = *(const ushort8v*)&sAB[o * 256 + kk * 8];
#pragma unroll
            for (int e = 0; e < 8; ++e) s += bf2f(hv[e]) * bf2f(wv[e]);
        }
        lg[p] = s + B2[o];
    }
    __syncthreads();

    float loss_l = 0.0f, cnt_l = 0.0f;
    if (tid < 64) {
        int lab = labels[row0 + tid];
        if (DO == 1) {
            float s = lg[tid];
            loss_l = fmaxf(s, 0.0f) + log1pf(__expf(-fabsf(s))) - (float)lab * s;
            int pred = (s > 0.0f) ? 1 : 0;
            cnt_l = (pred == lab) ? 1.0f : 0.0f;
        } else {
            const float* lr = &lg[tid * DO];
            float mx = lr[0];
            int am = 0;
#pragma unroll
            for (int o = 1; o < DO; ++o) {
                float v = lr[o];
                if (v > mx) { mx = v; am = o; }
            }
            float se = 0.0f;
#pragma unroll
            for (int o = 0; o < DO; ++o) se += __expf(lr[o] - mx);
            loss_l = mx + logf(se) - lr[lab];
            cnt_l = (am == lab) ? 1.0f : 0.0f;
        }
#pragma unroll
        for (int off = 32; off > 0; off >>= 1) {
            loss_l += __shfl_down(loss_l, off, 64);
            cnt_l  += __shfl_down(cnt_l, off, 64);
        }
        if (tid == 0) {
            atomicAdd(accum, loss_l);
            atomicAdd(accum + 1, cnt_l);
        }
    }
}

// ---------------------------------------------------------------------------
__global__ void finalize_kernel(const float* __restrict__ acc, float* __restrict__ out) {
    if (threadIdx.x == 0) {
        out[0] = (acc[0] + acc[2] + acc[4]) / (float)BATCH;
        out[1] = acc[3] / (float)NA;
        out[2] = acc[1] / (float)NT;
        out[3] = acc[5] / (float)NBD;
    }
}

// ---------------------------------------------------------------------------
extern "C" void kernel_launch(void* const* d_in, const int* in_sizes, int n_in,
                              void* d_out, int out_size, void* d_ws, size_t ws_size,
                              hipStream_t stream) {
    const float* src      = (const float*)d_in[0];
    const float* topoX    = (const float*)d_in[1];
    const float* atomX    = (const float*)d_in[2];
    const float* bondX    = (const float*)d_in[3];
    const int*   topo_idx = (const int*)d_in[4];
    const int*   atom_idx = (const int*)d_in[5];
    const int*   bond_idx = (const int*)d_in[6];
    const int*   topo_lab = (const int*)d_in[7];
    const int*   atom_lab = (const int*)d_in[8];
    const int*   bond_lab = (const int*)d_in[9];
    const float* Atw = (const float*)d_in[10]; const float* Atb = (const float*)d_in[11];
    const float* Aaw = (const float*)d_in[12]; const float* Aab = (const float*)d_in[13];
    const float* Abw = (const float*)d_in[14]; const float* Abb = (const float*)d_in[15];
    const float* tW1 = (const float*)d_in[16]; const float* tB1 = (const float*)d_in[17];
    const float* tW2 = (const float*)d_in[18]; const float* tB2 = (const float*)d_in[19];
    const float* aW1 = (const float*)d_in[20]; const float* aB1 = (const float*)d_in[21];
    const float* aW2 = (const float*)d_in[22]; const float* aB2 = (const float*)d_in[23];
    const float* bW1 = (const float*)d_in[24]; const float* bB1 = (const float*)d_in[25];
    const float* bW2 = (const float*)d_in[26]; const float* bB2 = (const float*)d_in[27];
    float* out = (float*)d_out;

    char* ws = (char*)d_ws;
    float* acc    = (float*)ws;                       // 8 f
    int*   cnt    = (int*)(ws + 256);                 // 3*256
    int*   cur    = (int*)(ws + 3328);                // 3*256
    int*   bstart = (int*)(ws + 6400);                // 3*256
    int*   bkt_t  = (int*)(ws + 9472);                // NT
    int*   bkt_a  = bkt_t + NT;
    int*   bkt_b  = bkt_a + NA;
    ushort_t* cxtb = (ushort_t*)(ws + 623872);        // NBD*32 bf16

    hipLaunchKernelGGL(init_kernel, dim3(1), dim3(256), 0, stream, acc, cnt);

    hipLaunchKernelGGL(hist_kernel, dim3(128), dim3(256), 0, stream, topo_idx, NT, cnt + 0);
    hipLaunchKernelGGL(hist_kernel, dim3(128), dim3(256), 0, stream, atom_idx, NA, cnt + 256);
    hipLaunchKernelGGL(hist_kernel, dim3(128), dim3(256), 0, stream, bond_idx, NBD, cnt + 512);
    hipLaunchKernelGGL(scan_kernel, dim3(1), dim3(256), 0, stream, cnt, cur, bstart);
    hipLaunchKernelGGL(scatter_kernel, dim3(256), dim3(256), 0, stream, topo_idx, NT, cur + 0, bkt_t);
    hipLaunchKernelGGL(scatter_kernel, dim3(256), dim3(256), 0, stream, atom_idx, NA, cur + 256, bkt_a);
    hipLaunchKernelGGL(scatter_kernel, dim3(256), dim3(256), 0, stream, bond_idx, NBD, cur + 512, bkt_b);

    // ---- topo head ----
    hipLaunchKernelGGL((attn_fused_kernel<512, 12>), dim3(256 * 12), dim3(256), 0, stream,
                       src, topoX, Atw, Atb, bkt_t, bstart + 0, cnt + 0, cxtb);
    hipLaunchKernelGGL((mlp_mfma_kernel<512, 1>), dim3(NT / 64), dim3(256), 0, stream,
                       topoX, cxtb, tW1, tB1, tW2, tB2, topo_lab, acc + 0, NT);

    // ---- atom head ----
    hipLaunchKernelGGL((attn_fused_kernel<512, 12>), dim3(256 * 12), dim3(256), 0, stream,
                       src, atomX, Aaw, Aab, bkt_a, bstart + 256, cnt + 256, cxtb);
    hipLaunchKernelGGL((mlp_mfma_kernel<512, 40>), dim3(NA / 64), dim3(256), 0, stream,
                       atomX, cxtb, aW1, aB1, aW2, aB2, atom_lab, acc + 2, NA);

    // ---- bond head ----
    hipLaunchKernelGGL((attn_fused_kernel<768, 20>), dim3(256 * 20), dim3(256), 0, stream,
                       src, bondX, Abw, Abb, bkt_b, bstart + 512, cnt + 512, cxtb);
    hipLaunchKernelGGL((mlp_mfma_kernel<768, 4>), dim3(NBD / 64), dim3(256), 0, stream,
                       bondX, cxtb, bW1, bB1, bW2, bB2, bond_lab, acc + 4, NBD);

    hipLaunchKernelGGL(finalize_kernel, dim3(1), dim3(64), 0, stream, acc, out);
}